// Round 4
// baseline (453.510 us; speedup 1.0000x reference)
//
#include <hip/hip_runtime.h>

#define MAXV 10000.0f

typedef float f32x4 __attribute__((ext_vector_type(4)));

__device__ __forceinline__ float min3f(float a, float b, float c) {
    return fminf(fminf(a, b), c);
}

// 3x3 erosion, fp32, (BC, H, W). Each thread: 4-wide x R-tall column strip.
// One float4 load per input row; horizontal halos come from neighbor lanes
// via __shfl (lanes 0/63 do a predicated scalar load for the cross-wave px).
// Fast path = all-active kernel (separable min3). Generic path = exact 9-tap
// with biases, matching reference fp32 arithmetic.
template <int R>
__global__ __launch_bounds__(256)
void erode3x3_rows(const float* __restrict__ x,
                   const float* __restrict__ kern,
                   float* __restrict__ out,
                   int H, int W) {
    const int tid  = threadIdx.x;
    const int lane = tid & 63;
    const int seg  = blockIdx.x * blockDim.x + tid;  // float4 index in row
    const int x0   = seg * 4;
    const int y0   = blockIdx.y * R;
    const long long bc = blockIdx.z;

    // structuring element (wave-uniform broadcast loads)
    float nv[3][3];
    bool all_active = true;
#pragma unroll
    for (int i = 0; i < 3; ++i)
#pragma unroll
        for (int j = 0; j < 3; ++j) {
            float kv = kern[i * 3 + j];
            nv[i][j] = (kv == 0.0f) ? -MAXV : 0.0f;
            all_active = all_active && (kv != 0.0f);
        }

    const float* base  = x   + bc * (long long)H * W;
    float*       obase = out + bc * (long long)H * W;

    if (all_active) {
        // separable: h = horizontal min3 (via lane shuffles), out = vertical min3
        f32x4 ha = {MAXV, MAXV, MAXV, MAXV};
        f32x4 hb = ha, hc = ha;
#pragma unroll
        for (int r = 0; r < R + 2; ++r) {
            const int ry = y0 - 1 + r;
            f32x4 h;
            if (ry >= 0 && ry < H) {
                const float* rp = base + (long long)ry * W + x0;
                const f32x4 b = *(const f32x4*)rp;
                float lw = __shfl_up(b.w, 1);    // lane-1's rightmost px
                float rx = __shfl_down(b.x, 1);  // lane+1's leftmost px
                if (lane == 0)  lw = (x0 > 0)     ? rp[-1] : MAXV;
                if (lane == 63) rx = (x0 + 4 < W) ? rp[4]  : MAXV;
                h.x = min3f(lw,  b.x, b.y);
                h.y = min3f(b.x, b.y, b.z);
                h.z = min3f(b.y, b.z, b.w);
                h.w = min3f(b.z, b.w, rx);
            } else {
                h = (f32x4){MAXV, MAXV, MAXV, MAXV};
            }
            ha = hb; hb = hc; hc = h;
            if (r >= 2) {
                f32x4 o;
                o.x = min3f(ha.x, hb.x, hc.x);
                o.y = min3f(ha.y, hb.y, hc.y);
                o.z = min3f(ha.z, hb.z, hc.z);
                o.w = min3f(ha.w, hb.w, hc.w);
                __builtin_nontemporal_store(
                    o, (f32x4*)(obase + (long long)(ry - 1) * W + x0));
            }
        }
    } else {
        // generic: raw 6-wide rows, exact 9-tap with biases
        float a0[6], a1[6], a2[6];
#pragma unroll
        for (int j = 0; j < 6; ++j) { a0[j] = a1[j] = a2[j] = MAXV; }
#pragma unroll
        for (int r = 0; r < R + 2; ++r) {
            const int ry = y0 - 1 + r;
            float cur[6];
            if (ry >= 0 && ry < H) {
                const float* rp = base + (long long)ry * W + x0;
                const f32x4 b = *(const f32x4*)rp;
                float lw = __shfl_up(b.w, 1);
                float rx = __shfl_down(b.x, 1);
                if (lane == 0)  lw = (x0 > 0)     ? rp[-1] : MAXV;
                if (lane == 63) rx = (x0 + 4 < W) ? rp[4]  : MAXV;
                cur[0] = lw;
                cur[1] = b.x; cur[2] = b.y; cur[3] = b.z; cur[4] = b.w;
                cur[5] = rx;
            } else {
#pragma unroll
                for (int j = 0; j < 6; ++j) cur[j] = MAXV;
            }
#pragma unroll
            for (int j = 0; j < 6; ++j) { a0[j] = a1[j]; a1[j] = a2[j]; a2[j] = cur[j]; }
            if (r >= 2) {
                float o[4];
#pragma unroll
                for (int e = 0; e < 4; ++e) {
                    float m = 3.4e38f;
#pragma unroll
                    for (int j = 0; j < 3; ++j) {
                        m = fminf(m, a0[e + j] - nv[0][j]);
                        m = fminf(m, a1[e + j] - nv[1][j]);
                        m = fminf(m, a2[e + j] - nv[2][j]);
                    }
                    o[e] = m;
                }
                f32x4 ov; ov.x = o[0]; ov.y = o[1]; ov.z = o[2]; ov.w = o[3];
                __builtin_nontemporal_store(
                    ov, (f32x4*)(obase + (long long)(ry - 1) * W + x0));
            }
        }
    }
}

extern "C" void kernel_launch(void* const* d_in, const int* in_sizes, int n_in,
                              void* d_out, int out_size, void* d_ws, size_t ws_size,
                              hipStream_t stream) {
    const float* x    = (const float*)d_in[0];
    const float* kern = (const float*)d_in[1];
    float* out        = (float*)d_out;

    const int H = 1024, W = 1024;
    constexpr int R = 16;                  // output rows per thread
    const int segs   = W / 4;              // 256 float4-segments per row
    const int ytiles = H / R;              // 64
    const int BC     = (int)((long long)out_size / ((long long)H * W));  // 64

    const int block = 256;
    dim3 grid((segs + block - 1) / block, ytiles, BC);

    erode3x3_rows<R><<<grid, block, 0, stream>>>(x, kern, out, H, W);
}